// Round 8
// baseline (163.773 us; speedup 1.0000x reference)
//
#include <hip/hip_runtime.h>
#include <stdint.h>

typedef unsigned short u16;
typedef __bf16 bf16x8 __attribute__((ext_vector_type(8)));
typedef float f32x4 __attribute__((ext_vector_type(4)));

#define M_PIX 12544   // 4*56*56 pixels
#define DIMC  512
#define NQKV  1536

static __device__ __forceinline__ u16 f2bf(float f) {
  union { float f; uint32_t u; } x; x.f = f;
  uint32_t r = x.u + 0x7FFFu + ((x.u >> 16) & 1u);
  return (u16)(r >> 16);
}

// ---- fused cast: X (fp32->bf16) then Wq|Wk|Wv -> Wc[1536][512] ----
__global__ void cast_all(const float* __restrict__ x, const float* __restrict__ Wq,
                         const float* __restrict__ Wk, const float* __restrict__ Wv,
                         u16* __restrict__ Xb, u16* __restrict__ Wc) {
  int idx = (blockIdx.x * 256 + threadIdx.x) * 4;
  const int NX = M_PIX * DIMC;
  const float* src;
  u16* dst;
  if (idx < NX) {
    src = x + idx; dst = Xb + idx;
  } else {
    int wi = idx - NX;
    if (wi >= NQKV * DIMC) return;
    int r = wi >> 9;
    int c = wi & 511;
    src = (r < 512)  ? (Wq + (size_t)r * 512 + c)
        : (r < 1024) ? (Wk + (size_t)(r - 512) * 512 + c)
                     : (Wv + (size_t)(r - 1024) * 512 + c);
    dst = Wc + wi;
  }
  float4 f = *(const float4*)src;
  uint32_t p0 = (uint32_t)f2bf(f.x) | ((uint32_t)f2bf(f.y) << 16);
  uint32_t p1 = (uint32_t)f2bf(f.z) | ((uint32_t)f2bf(f.w) << 16);
  *(uint2*)dst = make_uint2(p0, p1);
}

// ---- fused QKV GEMM: C[m][n] = sum_k A[m][k]*Wc[n][k] ----
// R8: launch_bounds 2 -> 4 blocks/CU (60 VGPR + 64 AGPR = 124 <= 128 cap).
// Barrier-drain stalls hide behind waves of co-resident blocks (m114 overlap).
__global__ __launch_bounds__(256, 4) void gemm_qkv(
    const u16* __restrict__ A, const u16* __restrict__ Bm,
    const float* __restrict__ bq, const float* __restrict__ bk,
    const float* __restrict__ bv, u16* __restrict__ qkv) {
  __shared__ u16 sA[128 * 32];
  __shared__ u16 sB[128 * 32];
  const int t = threadIdx.x;
  const int lane = t & 63;
  const int w = t >> 6;
  const int tile_m = blockIdx.x * 128;
  const int tile_n = blockIdx.y * 128;
  const int wm = (w & 1) * 64;
  const int wn = (w >> 1) * 64;
  const int quad = lane >> 4;
  const int l16 = lane & 15;

  f32x4 acc[4][4];
#pragma unroll
  for (int a = 0; a < 4; ++a)
#pragma unroll
    for (int bb = 0; bb < 4; ++bb) acc[a][bb] = (f32x4){0.f, 0.f, 0.f, 0.f};

  const int c0 = t, c1 = t + 256;
  const int r0 = c0 >> 2, ko0 = (c0 & 3) * 8;
  const int r1 = c1 >> 2, ko1 = (c1 & 3) * 8;
  const u16* gA0 = A + (size_t)(tile_m + r0) * DIMC + ko0;
  const u16* gA1 = A + (size_t)(tile_m + r1) * DIMC + ko1;
  const u16* gB0 = Bm + (size_t)(tile_n + r0) * DIMC + ko0;
  const u16* gB1 = Bm + (size_t)(tile_n + r1) * DIMC + ko1;
  u16* lA0 = sA + (size_t)(0 * 256 + (t & ~63)) * 8;
  u16* lA1 = sA + (size_t)(1 * 256 + (t & ~63)) * 8;
  u16* lB0 = sB + (size_t)(0 * 256 + (t & ~63)) * 8;
  u16* lB1 = sB + (size_t)(1 * 256 + (t & ~63)) * 8;

  for (int k0 = 0; k0 < DIMC; k0 += 32) {
    __builtin_amdgcn_global_load_lds((const __attribute__((address_space(1))) void*)(gA0 + k0),
                                     (__attribute__((address_space(3))) void*)lA0, 16, 0, 0);
    __builtin_amdgcn_global_load_lds((const __attribute__((address_space(1))) void*)(gA1 + k0),
                                     (__attribute__((address_space(3))) void*)lA1, 16, 0, 0);
    __builtin_amdgcn_global_load_lds((const __attribute__((address_space(1))) void*)(gB0 + k0),
                                     (__attribute__((address_space(3))) void*)lB0, 16, 0, 0);
    __builtin_amdgcn_global_load_lds((const __attribute__((address_space(1))) void*)(gB1 + k0),
                                     (__attribute__((address_space(3))) void*)lB1, 16, 0, 0);
    __syncthreads();

    bf16x8 af[4], bfr[4];
#pragma unroll
    for (int mt = 0; mt < 4; ++mt)
      af[mt] = *(const bf16x8*)(sA + (wm + mt * 16 + l16) * 32 + quad * 8);
#pragma unroll
    for (int nt = 0; nt < 4; ++nt)
      bfr[nt] = *(const bf16x8*)(sB + (wn + nt * 16 + l16) * 32 + quad * 8);
#pragma unroll
    for (int mt = 0; mt < 4; ++mt)
#pragma unroll
      for (int nt = 0; nt < 4; ++nt)
        acc[mt][nt] = __builtin_amdgcn_mfma_f32_16x16x32_bf16(bfr[nt], af[mt], acc[mt][nt], 0, 0, 0);
    __syncthreads();
  }

  const float qscale = 0.17677669529663687f;  // 1/sqrt(32)
#pragma unroll
  for (int mt = 0; mt < 4; ++mt) {
    const int m = tile_m + wm + mt * 16 + l16;
#pragma unroll
    for (int nt = 0; nt < 4; ++nt) {
      const int n0 = tile_n + wn + nt * 16 + quad * 4;
      const int mat = n0 >> 9;
      const int cc = n0 & 511;
      const float* bias = (mat == 0) ? bq : (mat == 1) ? bk : bv;
      const float4 bv4 = *(const float4*)(bias + cc);
      const float scl = (mat == 0) ? qscale : 1.0f;
      u16 h0 = f2bf((acc[mt][nt][0] + bv4.x) * scl);
      u16 h1 = f2bf((acc[mt][nt][1] + bv4.y) * scl);
      u16 h2 = f2bf((acc[mt][nt][2] + bv4.z) * scl);
      u16 h3 = f2bf((acc[mt][nt][3] + bv4.w) * scl);
      uint2 pk = make_uint2((uint32_t)h0 | ((uint32_t)h1 << 16),
                            (uint32_t)h2 | ((uint32_t)h3 << 16));
      *(uint2*)(qkv + (size_t)mat * M_PIX * DIMC + (size_t)m * DIMC + cc) = pk;
    }
  }
}

// ---- neighborhood attention v7 (unchanged): MFMA flash-style ----
__global__ __launch_bounds__(256, 4) void natten_k(const u16* __restrict__ qkv,
                                                   const float* __restrict__ rpb,
                                                   float* __restrict__ out) {
  __shared__ u16 uShared[11360];     // sK[0,8800) + sQ[8800,11360); sP aliases [0,10752)
  __shared__ u16 sVt[32 * 232];      // 14848 B, [dim][cand], stride 232
  __shared__ float sRpb[176];
  __shared__ uint32_t sTbl[320];     // [parity][160]: c | (r*13+c)<<8 ; 255 = invalid
  u16* sK = uShared;
  u16* sQ = uShared + 8800;
  u16* sP = uShared;

  const int tid = threadIdx.x;
  const int lane = tid & 63;
  const int w = tid >> 6;
  const int l16 = lane & 15;
  const int quad = lane >> 4;

  // decode block -> (head, b, ig, jg), XCD slab swizzle (28 pixel-row groups / XCD)
  const int bid = blockIdx.x;
  const int xcd = bid & 7;
  const int idx = bid >> 3;          // 0..447
  const int head = idx / 28;
  const int gl = idx - head * 28;
  const int g = xcd * 28 + gl;       // 0..223
  const int jg = g & 3;
  const int gi = g >> 2;             // 0..55
  const int b = gi / 14;
  const int ig = gi - b * 14;
  const int i0 = ig * 4, j0 = jg * 14;
  int c0 = j0 - 3; c0 = c0 < 0 ? 0 : (c0 > 36 ? 36 : c0);
  int nib = i0 - 3; nib = nib < 0 ? 0 : (nib > 49 ? 49 : nib);

  const int iw = i0 + w;
  int niw = iw - 3; niw = niw < 0 ? 0 : (niw > 49 ? 49 : niw);
  const int rowoff = niw - nib;       // 0..3
  const int par = rowoff & 1;
  const int woff2 = rowoff * 20 - par * 4;   // wave's slot0 -> tile cand (16B aligned in Vt)
  const int wconst = niw - iw + 6;

  const int qv = l16 < 14 ? l16 : 13;        // clamp pad queries for safe rpb idx
  const int jq = j0 + qv;
  int njq = jq - 3; njq = njq < 0 ? 0 : (njq > 49 ? 49 : njq);
  const uint32_t offq = (uint32_t)(njq - c0); // 0..13
  const int Cq = wconst * 13 + (c0 - jq + 6);

  const u16* Kpl = qkv + (size_t)M_PIX * DIMC;

  // ---- stage K: 220 cands x 4 dim-groups, 4 lanes/cand (vector LDS writes) ----
  for (int it = 0; it < 4; ++it) {
    int task = it * 256 + tid;
    if (task < 880) {
      int cand = task >> 2, dg = task & 3;
      int r = (cand * 205) >> 12;            // cand/20 for cand<220
      int c = cand - r * 20;
      int rimg = nib + r;
      uint4 kk = make_uint4(0, 0, 0, 0);
      if (rimg < 56) {
        size_t px = (size_t)((b * 56 + rimg) * 56 + c0 + c);
        kk = *(const uint4*)(Kpl + px * DIMC + head * 32 + dg * 8);
      }
      *(uint4*)((char*)sK + cand * 80 + dg * 16) = kk;
    }
  }
  // ---- stage V transposed, dim-major: lane = cand, loop dg (conflict-free writes) ----
  {
    const int cand = tid;
    if (cand < 220) {
      int r = (cand * 205) >> 12;
      int c = cand - r * 20;
      int rimg = nib + r;
      const bool ok = (rimg < 56);
      size_t px = (size_t)((b * 56 + rimg) * 56 + c0 + c);
      const u16* vsrc = Kpl + (size_t)M_PIX * DIMC + px * DIMC + head * 32;
      u16* vt = sVt + cand;
#pragma unroll
      for (int dg = 0; dg < 4; ++dg) {
        uint4 vv = ok ? *(const uint4*)(vsrc + dg * 8) : make_uint4(0, 0, 0, 0);
        int d0 = dg * 8;
        vt[(d0 + 0) * 232] = (u16)(vv.x & 0xFFFF); vt[(d0 + 1) * 232] = (u16)(vv.x >> 16);
        vt[(d0 + 2) * 232] = (u16)(vv.y & 0xFFFF); vt[(d0 + 3) * 232] = (u16)(vv.y >> 16);
        vt[(d0 + 4) * 232] = (u16)(vv.z & 0xFFFF); vt[(d0 + 5) * 232] = (u16)(vv.z >> 16);
        vt[(d0 + 6) * 232] = (u16)(vv.w & 0xFFFF); vt[(d0 + 7) * 232] = (u16)(vv.w >> 16);
      }
    }
  }
  // ---- stage Q per wave (rows 14,15 zeroed) ----
  {
    u16* sQw = sQ + w * 640;
    if (lane < 56) {
      int q = lane >> 2, dg = lane & 3;
      size_t px = (size_t)((b * 56 + iw) * 56 + j0 + q);
      uint4 qq = *(const uint4*)(qkv + px * DIMC + head * 32 + dg * 8);
      *(uint4*)((char*)sQw + q * 80 + dg * 16) = qq;
    } else {
      int tq = lane - 56;
      int q = 14 + (tq >> 2), dg = tq & 3;
      *(uint4*)((char*)sQw + q * 80 + dg * 16) = make_uint4(0, 0, 0, 0);
    }
  }
  if (tid < 169) sRpb[tid] = rpb[head * 169 + tid];
  for (int s2 = tid; s2 < 320; s2 += 256) {
    int pp = s2 >= 160 ? 1 : 0;
    int s = s2 - pp * 160;
    int t0 = s - pp * 4;
    uint32_t e = 255u;
    if (t0 >= 0 && t0 < 140) {
      int r = (t0 * 205) >> 12;
      int c = t0 - r * 20;
      e = (uint32_t)c | ((uint32_t)(r * 13 + c) << 8);
    }
    sTbl[s2] = e;
  }
  __syncthreads();

  // ---- S = Q.K^T : 10 MFMA chunks; S[ch][rg] = (cand woff2+ch*16+quad*4+rg, q=l16) ----
  u16* sQw = sQ + w * 640;
  u16* sPw = sP + w * 2688;
  const bf16x8 qf = *(const bf16x8*)((char*)sQw + l16 * 80 + quad * 16);
  f32x4 S[10];
#pragma unroll
  for (int ch = 0; ch < 10; ++ch) {
    bf16x8 kf = *(const bf16x8*)((char*)sK + (woff2 + ch * 16 + l16) * 80 + quad * 16);
    S[ch] = __builtin_amdgcn_mfma_f32_16x16x32_bf16(kf, qf, (f32x4){0.f, 0.f, 0.f, 0.f}, 0, 0, 0);
  }

  // sP aliases sK/sQ: all waves must finish their sK/sQ reads before P stores.
  __syncthreads();

  // ---- softmax (no max-sub: scores O(+-10) in fp32, safe) ----
  const float LOG2E = 1.4426950408889634f;
  float l = 0.f;
  const uint32_t* tb = sTbl + par * 160;
#pragma unroll
  for (int ch = 0; ch < 10; ++ch) {
    uint4 te = *(const uint4*)(tb + ch * 16 + quad * 4);
    float pv[4];
    uint32_t es[4] = {te.x, te.y, te.z, te.w};
#pragma unroll
    for (int rg = 0; rg < 4; ++rg) {
      uint32_t e = es[rg];
      uint32_t ce = e & 255u;
      bool valid = (ce - offq) < 7u;           // unsigned window test
      int ridx = valid ? (int)((e >> 8) & 255u) + Cq : 0;
      float rb = sRpb[ridx];
      float p = exp2f((S[ch][rg] + rb) * LOG2E);
      p = valid ? p : 0.f;
      pv[rg] = p;
      l += p;
    }
    uint2 pk = make_uint2((uint32_t)f2bf(pv[0]) | ((uint32_t)f2bf(pv[1]) << 16),
                          (uint32_t)f2bf(pv[2]) | ((uint32_t)f2bf(pv[3]) << 16));
    *(uint2*)((char*)sPw + l16 * 336 + ch * 32 + quad * 8) = pk;
  }
  l += __shfl_xor(l, 16);
  l += __shfl_xor(l, 32);

  // barrier between type-punned P store (uint2) and load (bf16x8)
  __syncthreads();

  // ---- O = P.V : 5 k-chunks x 2 dim-halves ----
  f32x4 O0 = (f32x4){0.f, 0.f, 0.f, 0.f};
  f32x4 O1 = (f32x4){0.f, 0.f, 0.f, 0.f};
#pragma unroll
  for (int c32 = 0; c32 < 5; ++c32) {
    bf16x8 pf = *(const bf16x8*)((char*)sPw + l16 * 336 + c32 * 64 + quad * 16);
    bf16x8 v0 = *(const bf16x8*)((char*)sVt + (0 + l16) * 464 + woff2 * 2 + c32 * 64 + quad * 16);
    bf16x8 v1 = *(const bf16x8*)((char*)sVt + (16 + l16) * 464 + woff2 * 2 + c32 * 64 + quad * 16);
    O0 = __builtin_amdgcn_mfma_f32_16x16x32_bf16(v0, pf, O0, 0, 0, 0);
    O1 = __builtin_amdgcn_mfma_f32_16x16x32_bf16(v1, pf, O1, 0, 0, 0);
  }

  // ---- write: lane holds q=l16, dims {quad*4+reg} and {16+quad*4+reg} ----
  if (l16 < 14) {
    const float inv = 1.0f / l;
    float* op = out + ((size_t)((b * 56 + iw) * 56 + j0 + l16)) * DIMC + head * 32;
    *(float4*)(op + quad * 4) =
        make_float4(O0[0] * inv, O0[1] * inv, O0[2] * inv, O0[3] * inv);
    *(float4*)(op + 16 + quad * 4) =
        make_float4(O1[0] * inv, O1[1] * inv, O1[2] * inv, O1[3] * inv);
  }
}

extern "C" void kernel_launch(void* const* d_in, const int* in_sizes, int n_in,
                              void* d_out, int out_size, void* d_ws, size_t ws_size,
                              hipStream_t stream) {
  const float* x   = (const float*)d_in[0];
  const float* Wq  = (const float*)d_in[1];
  const float* bq  = (const float*)d_in[2];
  const float* Wk  = (const float*)d_in[3];
  const float* bk  = (const float*)d_in[4];
  const float* Wv  = (const float*)d_in[5];
  const float* bv  = (const float*)d_in[6];
  const float* rpb = (const float*)d_in[7];
  float* out = (float*)d_out;

  u16* Xb  = (u16*)d_ws;
  u16* Wc  = Xb + (size_t)M_PIX * DIMC;
  u16* qkv = Wc + (size_t)NQKV * DIMC;

  const int ncast = (M_PIX * DIMC + NQKV * DIMC) / 4;
  cast_all<<<(ncast + 255) / 256, 256, 0, stream>>>(x, Wq, Wk, Wv, Xb, Wc);
  dim3 g(M_PIX / 128, NQKV / 128);  // 98 x 12
  gemm_qkv<<<g, 256, 0, stream>>>(Xb, Wc, bq, bk, bv, qkv);
  natten_k<<<16 * 224, 256, 0, stream>>>(qkv, rpb, out);   // 3584 blocks
}

// Round 9
// 161.071 us; speedup vs baseline: 1.0168x; 1.0168x over previous
//
#include <hip/hip_runtime.h>
#include <stdint.h>

typedef unsigned short u16;
typedef __bf16 bf16x8 __attribute__((ext_vector_type(8)));
typedef float f32x4 __attribute__((ext_vector_type(4)));

#define M_PIX 12544   // 4*56*56 pixels
#define DIMC  512
#define NQKV  1536

static __device__ __forceinline__ u16 f2bf(float f) {
  union { float f; uint32_t u; } x; x.f = f;
  uint32_t r = x.u + 0x7FFFu + ((x.u >> 16) & 1u);
  return (u16)(r >> 16);
}

// ---- fused cast: X (fp32->bf16) then Wq|Wk|Wv -> Wc[1536][512] ----
__global__ void cast_all(const float* __restrict__ x, const float* __restrict__ Wq,
                         const float* __restrict__ Wk, const float* __restrict__ Wv,
                         u16* __restrict__ Xb, u16* __restrict__ Wc) {
  int idx = (blockIdx.x * 256 + threadIdx.x) * 4;
  const int NX = M_PIX * DIMC;
  const float* src;
  u16* dst;
  if (idx < NX) {
    src = x + idx; dst = Xb + idx;
  } else {
    int wi = idx - NX;
    if (wi >= NQKV * DIMC) return;
    int r = wi >> 9;
    int c = wi & 511;
    src = (r < 512)  ? (Wq + (size_t)r * 512 + c)
        : (r < 1024) ? (Wk + (size_t)(r - 512) * 512 + c)
                     : (Wv + (size_t)(r - 1024) * 512 + c);
    dst = Wc + wi;
  }
  float4 f = *(const float4*)src;
  uint32_t p0 = (uint32_t)f2bf(f.x) | ((uint32_t)f2bf(f.y) << 16);
  uint32_t p1 = (uint32_t)f2bf(f.z) | ((uint32_t)f2bf(f.w) << 16);
  *(uint2*)dst = make_uint2(p0, p1);
}

// ---- fused QKV GEMM: C[m][n] = sum_k A[m][k]*Wc[n][k] ----
// R9: BK=64 via dual 128x32 half-buffers (8 global_load_lds + 32 MFMA per
// barrier pair; 8 barrier pairs vs 16). Same fragment geometry as the verified
// BK=32 kernel per half — no padded-stride (m104 trap avoided). LDS 32KB,
// 4 blocks/CU.
__global__ __launch_bounds__(256, 4) void gemm_qkv(
    const u16* __restrict__ A, const u16* __restrict__ Bm,
    const float* __restrict__ bq, const float* __restrict__ bk,
    const float* __restrict__ bv, u16* __restrict__ qkv) {
  __shared__ u16 sA[2][128 * 32];
  __shared__ u16 sB[2][128 * 32];
  const int t = threadIdx.x;
  const int lane = t & 63;
  const int w = t >> 6;
  const int tile_m = blockIdx.x * 128;
  const int tile_n = blockIdx.y * 128;
  const int wm = (w & 1) * 64;
  const int wn = (w >> 1) * 64;
  const int quad = lane >> 4;
  const int l16 = lane & 15;

  f32x4 acc[4][4];
#pragma unroll
  for (int a = 0; a < 4; ++a)
#pragma unroll
    for (int bb = 0; bb < 4; ++bb) acc[a][bb] = (f32x4){0.f, 0.f, 0.f, 0.f};

  const int c0 = t, c1 = t + 256;
  const int r0 = c0 >> 2, ko0 = (c0 & 3) * 8;
  const int r1 = c1 >> 2, ko1 = (c1 & 3) * 8;
  const u16* gA0 = A + (size_t)(tile_m + r0) * DIMC + ko0;
  const u16* gA1 = A + (size_t)(tile_m + r1) * DIMC + ko1;
  const u16* gB0 = Bm + (size_t)(tile_n + r0) * DIMC + ko0;
  const u16* gB1 = Bm + (size_t)(tile_n + r1) * DIMC + ko1;
  const int ldsoff = (t & ~63) * 8;   // wave-uniform base; HW adds lane*16B

  for (int k0 = 0; k0 < DIMC; k0 += 64) {
#pragma unroll
    for (int h = 0; h < 2; ++h) {
      // h*32 elems = 64B immediate offset into the same 4 base pointers
      __builtin_amdgcn_global_load_lds(
          (const __attribute__((address_space(1))) void*)(gA0 + k0 + h * 32),
          (__attribute__((address_space(3))) void*)(sA[h] + 0 * 2048 + ldsoff), 16, 0, 0);
      __builtin_amdgcn_global_load_lds(
          (const __attribute__((address_space(1))) void*)(gA1 + k0 + h * 32),
          (__attribute__((address_space(3))) void*)(sA[h] + 1 * 2048 + ldsoff), 16, 0, 0);
      __builtin_amdgcn_global_load_lds(
          (const __attribute__((address_space(1))) void*)(gB0 + k0 + h * 32),
          (__attribute__((address_space(3))) void*)(sB[h] + 0 * 2048 + ldsoff), 16, 0, 0);
      __builtin_amdgcn_global_load_lds(
          (const __attribute__((address_space(1))) void*)(gB1 + k0 + h * 32),
          (__attribute__((address_space(3))) void*)(sB[h] + 1 * 2048 + ldsoff), 16, 0, 0);
    }
    __syncthreads();

#pragma unroll
    for (int h = 0; h < 2; ++h) {
      bf16x8 af[4], bfr[4];
#pragma unroll
      for (int mt = 0; mt < 4; ++mt)
        af[mt] = *(const bf16x8*)(sA[h] + (wm + mt * 16 + l16) * 32 + quad * 8);
#pragma unroll
      for (int nt = 0; nt < 4; ++nt)
        bfr[nt] = *(const bf16x8*)(sB[h] + (wn + nt * 16 + l16) * 32 + quad * 8);
#pragma unroll
      for (int mt = 0; mt < 4; ++mt)
#pragma unroll
        for (int nt = 0; nt < 4; ++nt)
          acc[mt][nt] = __builtin_amdgcn_mfma_f32_16x16x32_bf16(bfr[nt], af[mt], acc[mt][nt], 0, 0, 0);
    }
    __syncthreads();
  }

  const float qscale = 0.17677669529663687f;  // 1/sqrt(32)
#pragma unroll
  for (int mt = 0; mt < 4; ++mt) {
    const int m = tile_m + wm + mt * 16 + l16;
#pragma unroll
    for (int nt = 0; nt < 4; ++nt) {
      const int n0 = tile_n + wn + nt * 16 + quad * 4;
      const int mat = n0 >> 9;
      const int cc = n0 & 511;
      const float* bias = (mat == 0) ? bq : (mat == 1) ? bk : bv;
      const float4 bv4 = *(const float4*)(bias + cc);
      const float scl = (mat == 0) ? qscale : 1.0f;
      u16 h0 = f2bf((acc[mt][nt][0] + bv4.x) * scl);
      u16 h1 = f2bf((acc[mt][nt][1] + bv4.y) * scl);
      u16 h2 = f2bf((acc[mt][nt][2] + bv4.z) * scl);
      u16 h3 = f2bf((acc[mt][nt][3] + bv4.w) * scl);
      uint2 pk = make_uint2((uint32_t)h0 | ((uint32_t)h1 << 16),
                            (uint32_t)h2 | ((uint32_t)h3 << 16));
      *(uint2*)(qkv + (size_t)mat * M_PIX * DIMC + (size_t)m * DIMC + cc) = pk;
    }
  }
}

// ---- neighborhood attention v7 (unchanged): MFMA flash-style ----
__global__ __launch_bounds__(256, 4) void natten_k(const u16* __restrict__ qkv,
                                                   const float* __restrict__ rpb,
                                                   float* __restrict__ out) {
  __shared__ u16 uShared[11360];     // sK[0,8800) + sQ[8800,11360); sP aliases [0,10752)
  __shared__ u16 sVt[32 * 232];      // 14848 B, [dim][cand], stride 232
  __shared__ float sRpb[176];
  __shared__ uint32_t sTbl[320];     // [parity][160]: c | (r*13+c)<<8 ; 255 = invalid
  u16* sK = uShared;
  u16* sQ = uShared + 8800;
  u16* sP = uShared;

  const int tid = threadIdx.x;
  const int lane = tid & 63;
  const int w = tid >> 6;
  const int l16 = lane & 15;
  const int quad = lane >> 4;

  // decode block -> (head, b, ig, jg), XCD slab swizzle (28 pixel-row groups / XCD)
  const int bid = blockIdx.x;
  const int xcd = bid & 7;
  const int idx = bid >> 3;          // 0..447
  const int head = idx / 28;
  const int gl = idx - head * 28;
  const int g = xcd * 28 + gl;       // 0..223
  const int jg = g & 3;
  const int gi = g >> 2;             // 0..55
  const int b = gi / 14;
  const int ig = gi - b * 14;
  const int i0 = ig * 4, j0 = jg * 14;
  int c0 = j0 - 3; c0 = c0 < 0 ? 0 : (c0 > 36 ? 36 : c0);
  int nib = i0 - 3; nib = nib < 0 ? 0 : (nib > 49 ? 49 : nib);

  const int iw = i0 + w;
  int niw = iw - 3; niw = niw < 0 ? 0 : (niw > 49 ? 49 : niw);
  const int rowoff = niw - nib;       // 0..3
  const int par = rowoff & 1;
  const int woff2 = rowoff * 20 - par * 4;   // wave's slot0 -> tile cand (16B aligned in Vt)
  const int wconst = niw - iw + 6;

  const int qv = l16 < 14 ? l16 : 13;        // clamp pad queries for safe rpb idx
  const int jq = j0 + qv;
  int njq = jq - 3; njq = njq < 0 ? 0 : (njq > 49 ? 49 : njq);
  const uint32_t offq = (uint32_t)(njq - c0); // 0..13
  const int Cq = wconst * 13 + (c0 - jq + 6);

  const u16* Kpl = qkv + (size_t)M_PIX * DIMC;

  // ---- stage K: 220 cands x 4 dim-groups, 4 lanes/cand (vector LDS writes) ----
  for (int it = 0; it < 4; ++it) {
    int task = it * 256 + tid;
    if (task < 880) {
      int cand = task >> 2, dg = task & 3;
      int r = (cand * 205) >> 12;            // cand/20 for cand<220
      int c = cand - r * 20;
      int rimg = nib + r;
      uint4 kk = make_uint4(0, 0, 0, 0);
      if (rimg < 56) {
        size_t px = (size_t)((b * 56 + rimg) * 56 + c0 + c);
        kk = *(const uint4*)(Kpl + px * DIMC + head * 32 + dg * 8);
      }
      *(uint4*)((char*)sK + cand * 80 + dg * 16) = kk;
    }
  }
  // ---- stage V transposed, dim-major: lane = cand, loop dg (conflict-free writes) ----
  {
    const int cand = tid;
    if (cand < 220) {
      int r = (cand * 205) >> 12;
      int c = cand - r * 20;
      int rimg = nib + r;
      const bool ok = (rimg < 56);
      size_t px = (size_t)((b * 56 + rimg) * 56 + c0 + c);
      const u16* vsrc = Kpl + (size_t)M_PIX * DIMC + px * DIMC + head * 32;
      u16* vt = sVt + cand;
#pragma unroll
      for (int dg = 0; dg < 4; ++dg) {
        uint4 vv = ok ? *(const uint4*)(vsrc + dg * 8) : make_uint4(0, 0, 0, 0);
        int d0 = dg * 8;
        vt[(d0 + 0) * 232] = (u16)(vv.x & 0xFFFF); vt[(d0 + 1) * 232] = (u16)(vv.x >> 16);
        vt[(d0 + 2) * 232] = (u16)(vv.y & 0xFFFF); vt[(d0 + 3) * 232] = (u16)(vv.y >> 16);
        vt[(d0 + 4) * 232] = (u16)(vv.z & 0xFFFF); vt[(d0 + 5) * 232] = (u16)(vv.z >> 16);
        vt[(d0 + 6) * 232] = (u16)(vv.w & 0xFFFF); vt[(d0 + 7) * 232] = (u16)(vv.w >> 16);
      }
    }
  }
  // ---- stage Q per wave (rows 14,15 zeroed) ----
  {
    u16* sQw = sQ + w * 640;
    if (lane < 56) {
      int q = lane >> 2, dg = lane & 3;
      size_t px = (size_t)((b * 56 + iw) * 56 + j0 + q);
      uint4 qq = *(const uint4*)(qkv + px * DIMC + head * 32 + dg * 8);
      *(uint4*)((char*)sQw + q * 80 + dg * 16) = qq;
    } else {
      int tq = lane - 56;
      int q = 14 + (tq >> 2), dg = tq & 3;
      *(uint4*)((char*)sQw + q * 80 + dg * 16) = make_uint4(0, 0, 0, 0);
    }
  }
  if (tid < 169) sRpb[tid] = rpb[head * 169 + tid];
  for (int s2 = tid; s2 < 320; s2 += 256) {
    int pp = s2 >= 160 ? 1 : 0;
    int s = s2 - pp * 160;
    int t0 = s - pp * 4;
    uint32_t e = 255u;
    if (t0 >= 0 && t0 < 140) {
      int r = (t0 * 205) >> 12;
      int c = t0 - r * 20;
      e = (uint32_t)c | ((uint32_t)(r * 13 + c) << 8);
    }
    sTbl[s2] = e;
  }
  __syncthreads();

  // ---- S = Q.K^T : 10 MFMA chunks; S[ch][rg] = (cand woff2+ch*16+quad*4+rg, q=l16) ----
  u16* sQw = sQ + w * 640;
  u16* sPw = sP + w * 2688;
  const bf16x8 qf = *(const bf16x8*)((char*)sQw + l16 * 80 + quad * 16);
  f32x4 S[10];
#pragma unroll
  for (int ch = 0; ch < 10; ++ch) {
    bf16x8 kf = *(const bf16x8*)((char*)sK + (woff2 + ch * 16 + l16) * 80 + quad * 16);
    S[ch] = __builtin_amdgcn_mfma_f32_16x16x32_bf16(kf, qf, (f32x4){0.f, 0.f, 0.f, 0.f}, 0, 0, 0);
  }

  // sP aliases sK/sQ: all waves must finish their sK/sQ reads before P stores.
  __syncthreads();

  // ---- softmax (no max-sub: scores O(+-10) in fp32, safe) ----
  const float LOG2E = 1.4426950408889634f;
  float l = 0.f;
  const uint32_t* tb = sTbl + par * 160;
#pragma unroll
  for (int ch = 0; ch < 10; ++ch) {
    uint4 te = *(const uint4*)(tb + ch * 16 + quad * 4);
    float pv[4];
    uint32_t es[4] = {te.x, te.y, te.z, te.w};
#pragma unroll
    for (int rg = 0; rg < 4; ++rg) {
      uint32_t e = es[rg];
      uint32_t ce = e & 255u;
      bool valid = (ce - offq) < 7u;           // unsigned window test
      int ridx = valid ? (int)((e >> 8) & 255u) + Cq : 0;
      float rb = sRpb[ridx];
      float p = exp2f((S[ch][rg] + rb) * LOG2E);
      p = valid ? p : 0.f;
      pv[rg] = p;
      l += p;
    }
    uint2 pk = make_uint2((uint32_t)f2bf(pv[0]) | ((uint32_t)f2bf(pv[1]) << 16),
                          (uint32_t)f2bf(pv[2]) | ((uint32_t)f2bf(pv[3]) << 16));
    *(uint2*)((char*)sPw + l16 * 336 + ch * 32 + quad * 8) = pk;
  }
  l += __shfl_xor(l, 16);
  l += __shfl_xor(l, 32);

  // barrier between type-punned P store (uint2) and load (bf16x8)
  __syncthreads();

  // ---- O = P.V : 5 k-chunks x 2 dim-halves ----
  f32x4 O0 = (f32x4){0.f, 0.f, 0.f, 0.f};
  f32x4 O1 = (f32x4){0.f, 0.f, 0.f, 0.f};
#pragma unroll
  for (int c32 = 0; c32 < 5; ++c32) {
    bf16x8 pf = *(const bf16x8*)((char*)sPw + l16 * 336 + c32 * 64 + quad * 16);
    bf16x8 v0 = *(const bf16x8*)((char*)sVt + (0 + l16) * 464 + woff2 * 2 + c32 * 64 + quad * 16);
    bf16x8 v1 = *(const bf16x8*)((char*)sVt + (16 + l16) * 464 + woff2 * 2 + c32 * 64 + quad * 16);
    O0 = __builtin_amdgcn_mfma_f32_16x16x32_bf16(v0, pf, O0, 0, 0, 0);
    O1 = __builtin_amdgcn_mfma_f32_16x16x32_bf16(v1, pf, O1, 0, 0, 0);
  }

  // ---- write: lane holds q=l16, dims {quad*4+reg} and {16+quad*4+reg} ----
  if (l16 < 14) {
    const float inv = 1.0f / l;
    float* op = out + ((size_t)((b * 56 + iw) * 56 + j0 + l16)) * DIMC + head * 32;
    *(float4*)(op + quad * 4) =
        make_float4(O0[0] * inv, O0[1] * inv, O0[2] * inv, O0[3] * inv);
    *(float4*)(op + 16 + quad * 4) =
        make_float4(O1[0] * inv, O1[1] * inv, O1[2] * inv, O1[3] * inv);
  }
}

extern "C" void kernel_launch(void* const* d_in, const int* in_sizes, int n_in,
                              void* d_out, int out_size, void* d_ws, size_t ws_size,
                              hipStream_t stream) {
  const float* x   = (const float*)d_in[0];
  const float* Wq  = (const float*)d_in[1];
  const float* bq  = (const float*)d_in[2];
  const float* Wk  = (const float*)d_in[3];
  const float* bk  = (const float*)d_in[4];
  const float* Wv  = (const float*)d_in[5];
  const float* bv  = (const float*)d_in[6];
  const float* rpb = (const float*)d_in[7];
  float* out = (float*)d_out;

  u16* Xb  = (u16*)d_ws;
  u16* Wc  = Xb + (size_t)M_PIX * DIMC;
  u16* qkv = Wc + (size_t)NQKV * DIMC;

  const int ncast = (M_PIX * DIMC + NQKV * DIMC) / 4;
  cast_all<<<(ncast + 255) / 256, 256, 0, stream>>>(x, Wq, Wk, Wv, Xb, Wc);
  dim3 g(M_PIX / 128, NQKV / 128);  // 98 x 12
  gemm_qkv<<<g, 256, 0, stream>>>(Xb, Wc, bq, bk, bv, qkv);
  natten_k<<<16 * 224, 256, 0, stream>>>(qkv, rpb, out);   // 3584 blocks
}